// Round 13
// baseline (117.010 us; speedup 1.0000x reference)
//
#include <hip/hip_runtime.h>
#include <hip/hip_bf16.h>
#include <stdint.h>

#define M_DIM 2048
#define K_DIM 4096
#define N_DIM 4096

typedef __attribute__((ext_vector_type(8))) short short8;
typedef __attribute__((ext_vector_type(4))) float f32x4;

#define MFMA __builtin_amdgcn_mfma_f32_16x16x32_bf16

// RNE float -> bf16, packed pair
__device__ __forceinline__ uint32_t bf16pk(float a, float b) {
  uint32_t ua = __float_as_uint(a);
  ua = (ua + 0x7FFFu + ((ua >> 16) & 1u)) >> 16;
  uint32_t ub = __float_as_uint(b);
  ub = (ub + 0x7FFFu + ((ub >> 16) & 1u)) >> 16;
  return ua | (ub << 16);
}

__device__ __forceinline__ void glds16(const char* g, char* l) {
  __builtin_amdgcn_global_load_lds((__attribute__((address_space(1))) void*)g,
                                   (__attribute__((address_space(3))) void*)l, 16, 0, 0);
}

// ---------------------------------------------------------------------------
// Image layout: BK=32 steps, 8KB tiles, [k8-slot 0..3][row 0..127][16B].
//  xImg[mt 0..15][step 0..127]  (16.78 MB): x[mt*128+row][step*32+slot*8+e]
//  wImg[nt 0..31][step 0..127]  (33.55 MB): W[step*32+slot*8+e][nt*128+col]
// Verified R6-R12 (0 bank conflicts; index algebra checked).
// ---------------------------------------------------------------------------

// Merged prepass (R8-verified bodies): grid 3072 x 256.
__global__ void __launch_bounds__(256) prep_kernel(const float* __restrict__ x,
                                                   const uint32_t* __restrict__ qweight,
                                                   const uint32_t* __restrict__ qzeros,
                                                   const float* __restrict__ scales,
                                                   char* __restrict__ xImg,
                                                   char* __restrict__ wImg) {
  const int tid = threadIdx.x;
  if (blockIdx.x < 1024) {
    const int bid = blockIdx.x;
    const int mt = bid >> 6, ktp = bid & 63;
    const int row = tid & 127, sh = tid >> 7;
    const int s = ktp * 2 + sh;
    const float* src = x + (size_t)(mt * 128 + row) * K_DIM + s * 32;
    char* dst = xImg + (size_t)(mt * 128 + s) * 8192 + row * 16;
#pragma unroll
    for (int slot = 0; slot < 4; ++slot) {
      float4 f0 = *(const float4*)(src + slot * 8);
      float4 f1 = *(const float4*)(src + slot * 8 + 4);
      uint4 pk;
      pk.x = bf16pk(f0.x, f0.y);
      pk.y = bf16pk(f0.z, f0.w);
      pk.z = bf16pk(f1.x, f1.y);
      pk.w = bf16pk(f1.z, f1.w);
      *(uint4*)(dst + slot * 2048) = pk;
    }
  } else {
    const int bid = blockIdx.x - 1024;
    const int nt = bid >> 6, ktp = bid & 63;
    const int n = tid & 127, sh = tid >> 7;
    const int s = ktp * 2 + sh;
    const int g = ktp >> 1;                    // group = 128 k = 4 steps
    const int gn = nt * 128 + n;
    uint32_t zq = qzeros[g * (N_DIM / 8) + (gn >> 3)];
    const int z = (int)((zq >> ((gn & 7) * 4)) & 15u) + 1;
    const float s_ = scales[g * N_DIM + gn];
    char* dst = wImg + (size_t)(nt * 128 + s) * 8192 + n * 16;
#pragma unroll
    for (int slot = 0; slot < 4; ++slot) {
      uint32_t q = qweight[(size_t)(s * 4 + slot) * N_DIM + gn];
      float f[8];
#pragma unroll
      for (int v = 0; v < 8; ++v) {
        int w = (int)((q >> (4 * v)) & 15u);
        f[v] = (float)(w - z) * s_;            // exact int sub, cvt, mul
      }
      uint4 pk;
      pk.x = bf16pk(f[0], f[1]);
      pk.y = bf16pk(f[2], f[3]);
      pk.z = bf16pk(f[4], f[5]);
      pk.w = bf16pk(f[6], f[7]);
      *(uint4*)(dst + slot * 2048) = pk;
    }
  }
}

// ---------------------------------------------------------------------------
// GEMM: LDS-BANDWIDTH reduction build.
// Diagnosis (R8-R12): kernel is LDS-PORT-bound -- staging writes + ds_reads
// share the ~85-128 B/cyc port; R8 moved 80KB/block-step (2 blocks/CU), so
// the port alone costs ~50us. Fix: 4 FAT waves (1/SIMD), per-wave 128x64,
// BM=128 BN=256, full K (no split/reduce/exchange), grid 256 = 1 block/CU.
// Per step: stage 24KB + reads 48KB = 72KB/CU (2.2x less LDS traffic per
// K-work) -> LDS 565-847 cyc vs MFMA 620 cyc: balanced, overlappable.
//
// Ring-3 x 24KB slots, R12-verified early-read ledger:
//   step t: reads(t+1) from slot (t+1)%3  [staged at t-1, drained+bar'd]
//           STAGE(t+2) -> slot (t+2)%3    [its step-(t-1) reads done:
//                                          lgkm before MFMA(t-1) + barrier]
//           lgkmcnt(12) -> reads(t) done (12 newest = reads(t+1) in flight)
//           32 MFMA on set t&1 (static idx via unroll 2)
//           vmcnt(0) -> own STAGE(t+2) landed BEFORE barrier (race-safe)
// Tail: t=126 no stage; t=127 no reads, lgkmcnt(0), no barrier.
// ---------------------------------------------------------------------------
__global__ void __launch_bounds__(256, 1) gemm_kernel(const char* __restrict__ xImg,
                                                      const char* __restrict__ wImg,
                                                      const float* __restrict__ bias,
                                                      float* __restrict__ out) {
  __shared__ uint4 ldsv[4608];                 // 73728 B = 3 slots x 24KB
  char* lds = (char*)ldsv;
  const int tid = threadIdx.x;
  const int lane = tid & 63, wc = tid >> 6;    // 4 waves, N-split (1M x 4N)
  const int lr = lane & 15, lk = lane >> 4;

  // XCD swizzle: xcd = bid&7 owns nb pair (2 x 2MB B panels = L2) x all mb
  const int bid = blockIdx.x;                  // 256 blocks
  const int xcd = bid & 7, local = bid >> 3;
  const int nb = xcd * 2 + (local & 1);        // 0..15
  const int mb = local >> 1;                   // 0..15

  f32x4 acc[8][4];
#pragma unroll
  for (int i = 0; i < 8; ++i)
#pragma unroll
    for (int j = 0; j < 4; ++j) acc[i][j] = f32x4{0.f, 0.f, 0.f, 0.f};

  const char* aT = xImg + (size_t)mb * 128 * 8192;            // steps 0..127
  const char* bT0 = wImg + (size_t)(2 * nb) * 128 * 8192;     // cols 0-127
  const char* bT1 = wImg + (size_t)(2 * nb + 1) * 128 * 8192; // cols 128-255

  // slot layout (24KB): A[0,8K) B0[8K,16K) B1[16K,24K)
  int aoff[8], boff[4];
#pragma unroll
  for (int i = 0; i < 8; ++i) aoff[i] = lk * 2048 + (i * 16 + lr) * 16;
#pragma unroll
  for (int j = 0; j < 4; ++j)
    boff[j] = 8192 + (wc >> 1) * 8192 + lk * 2048 + ((wc & 1) * 64 + j * 16 + lr) * 16;

#define STAGE(T, SLOT)                                                      \
  do {                                                                      \
    char* d = lds + (SLOT) * 24576;                                         \
    glds16(aT + (size_t)(T) * 8192 + tid * 16, d + tid * 16);               \
    glds16(aT + (size_t)(T) * 8192 + 4096 + tid * 16, d + 4096 + tid * 16); \
    glds16(bT0 + (size_t)(T) * 8192 + tid * 16, d + 8192 + tid * 16);       \
    glds16(bT0 + (size_t)(T) * 8192 + 4096 + tid * 16, d + 12288 + tid * 16);\
    glds16(bT1 + (size_t)(T) * 8192 + tid * 16, d + 16384 + tid * 16);      \
    glds16(bT1 + (size_t)(T) * 8192 + 4096 + tid * 16, d + 20480 + tid * 16);\
  } while (0)

  short8 vA[2][8], vB[2][4];

  // prologue (R12-verified pattern): stage0, drain, bar; reads(0); stage1, drain, bar
  STAGE(0, 0);
  asm volatile("s_waitcnt vmcnt(0)" ::: "memory");
  __builtin_amdgcn_sched_barrier(0);
  __builtin_amdgcn_s_barrier();
#pragma unroll
  for (int i = 0; i < 8; ++i) vA[0][i] = *(const short8*)(lds + aoff[i]);
#pragma unroll
  for (int j = 0; j < 4; ++j) vB[0][j] = *(const short8*)(lds + boff[j]);
  STAGE(1, 1);
  asm volatile("s_waitcnt vmcnt(0)" ::: "memory");
  __builtin_amdgcn_sched_barrier(0);
  __builtin_amdgcn_s_barrier();

#pragma unroll 2
  for (int t = 0; t < 128; ++t) {
    const int cs = t & 1, ns = cs ^ 1;

    // 1. reads(t+1) -- early; drain under this step's MFMA
    if (t < 127) {
      const char* rbuf = lds + ((t + 1) % 3) * 24576;
#pragma unroll
      for (int i = 0; i < 8; ++i) vA[ns][i] = *(const short8*)(rbuf + aoff[i]);
#pragma unroll
      for (int j = 0; j < 4; ++j) vB[ns][j] = *(const short8*)(rbuf + boff[j]);
    }
    // 2. stage(t+2)
    if (t < 126) STAGE(t + 2, (t + 2) % 3);
    __builtin_amdgcn_sched_barrier(0);

    // 3. counted wait: reads(t) complete (12 newest = reads(t+1) in flight)
    if (t < 127) asm volatile("s_waitcnt lgkmcnt(12)" ::: "memory");
    else         asm volatile("s_waitcnt lgkmcnt(0)" ::: "memory");
    __builtin_amdgcn_sched_barrier(0);

    __builtin_amdgcn_s_setprio(1);
#pragma unroll
    for (int j = 0; j < 4; ++j) {
#pragma unroll
      for (int i = 0; i < 8; ++i)
        acc[i][j] = MFMA(vA[cs][i], vB[cs][j], acc[i][j], 0, 0, 0);
    }
    __builtin_amdgcn_s_setprio(0);

    if (t < 127) {
      asm volatile("s_waitcnt vmcnt(0)" ::: "memory");   // own stage(t+2) landed
      __builtin_amdgcn_sched_barrier(0);
      __builtin_amdgcn_s_barrier();                      // globalize
    }
  }
#undef STAGE

  // epilogue: direct store (full K per block -> no exchange/reduce).
  // C/D map col=lane&15, row=(lane>>4)*4+reg (verified R0-R12)
  const int colB = nb * 256 + wc * 64 + lr;
#pragma unroll
  for (int j = 0; j < 4; ++j) {
    int col = colB + j * 16;
    float bj = bias[col];
#pragma unroll
    for (int i = 0; i < 8; ++i) {
      int row = mb * 128 + i * 16 + lk * 4;
#pragma unroll
      for (int r = 0; r < 4; ++r)
        out[(size_t)(row + r) * N_DIM + col] = acc[i][j][r] + bj;
    }
  }
}

// ---------------------------------------------------------------------------
// Fallback (workspace too small)
// ---------------------------------------------------------------------------
__global__ void fallback_kernel(const float* __restrict__ x, const uint32_t* __restrict__ qweight,
                                const uint32_t* __restrict__ qzeros, const float* __restrict__ scales,
                                const float* __restrict__ bias, float* __restrict__ out) {
  __shared__ float xs[16][17];
  __shared__ float ws[16][17];
  int tx = threadIdx.x, ty = threadIdx.y;
  int col = blockIdx.x * 16 + tx;
  int row = blockIdx.y * 16 + ty;
  float acc = 0.f;
  for (int k0 = 0; k0 < K_DIM; k0 += 16) {
    xs[ty][tx] = x[(size_t)row * K_DIM + k0 + tx];
    int k = k0 + ty;
    int g = k >> 7;
    uint32_t q = qweight[(size_t)(k >> 3) * N_DIM + col];
    int w = (int)((q >> ((k & 7) * 4)) & 15u);
    uint32_t zq = qzeros[g * (N_DIM / 8) + (col >> 3)];
    int z = (int)((zq >> ((col & 7) * 4)) & 15u) + 1;
    ws[ty][tx] = (float)(w - z) * scales[g * N_DIM + col];
    __syncthreads();
#pragma unroll
    for (int kk = 0; kk < 16; ++kk) acc += xs[ty][kk] * ws[kk][tx];
    __syncthreads();
  }
  out[(size_t)row * N_DIM + col] = acc + bias[col];
}

extern "C" void kernel_launch(void* const* d_in, const int* in_sizes, int n_in,
                              void* d_out, int out_size, void* d_ws, size_t ws_size,
                              hipStream_t stream) {
  const float* x = (const float*)d_in[0];
  const uint32_t* qweight = (const uint32_t*)d_in[1];
  const uint32_t* qzeros = (const uint32_t*)d_in[2];
  const float* scales = (const float*)d_in[3];
  // d_in[4] = g_idx (== arange(K)//128, folded into index math)
  const float* bias = (const float*)d_in[5];
  float* out = (float*)d_out;

  const size_t X_IMG = (size_t)16 * 128 * 8192;   // 16.78 MB
  const size_t W_IMG = (size_t)32 * 128 * 8192;   // 33.55 MB

  if (ws_size >= X_IMG + W_IMG) {
    char* xImg = (char*)d_ws;
    char* wImg = (char*)d_ws + X_IMG;
    prep_kernel<<<3072, 256, 0, stream>>>(x, qweight, qzeros, scales, xImg, wImg);
    gemm_kernel<<<256, 256, 0, stream>>>(xImg, wImg, bias, out);
  } else {
    fallback_kernel<<<dim3(N_DIM / 16, M_DIM / 16), dim3(16, 16), 0, stream>>>(
        x, qweight, qzeros, scales, bias, out);
  }
}

// Round 14
// 97.193 us; speedup vs baseline: 1.2039x; 1.2039x over previous
//
#include <hip/hip_runtime.h>
#include <hip/hip_bf16.h>
#include <stdint.h>

#define M_DIM 2048
#define K_DIM 4096
#define N_DIM 4096

typedef __attribute__((ext_vector_type(8))) short short8;
typedef __attribute__((ext_vector_type(4))) float f32x4;

#define MFMA __builtin_amdgcn_mfma_f32_16x16x32_bf16

// RNE float -> bf16, packed pair
__device__ __forceinline__ uint32_t bf16pk(float a, float b) {
  uint32_t ua = __float_as_uint(a);
  ua = (ua + 0x7FFFu + ((ua >> 16) & 1u)) >> 16;
  uint32_t ub = __float_as_uint(b);
  ub = (ub + 0x7FFFu + ((ub >> 16) & 1u)) >> 16;
  return ua | (ub << 16);
}

__device__ __forceinline__ void glds16(const char* g, char* l) {
  __builtin_amdgcn_global_load_lds((__attribute__((address_space(1))) void*)g,
                                   (__attribute__((address_space(3))) void*)l, 16, 0, 0);
}

// ---------------------------------------------------------------------------
// Image layout: BK=32 steps, 8KB tiles, [k8-slot 0..3][row 0..127][16B].
//  xImg[mt 0..15][step 0..127]  (16.78 MB)
//  wImg[nt 0..31][step 0..127]  (33.55 MB)
// Verified R6-R13 (0 bank conflicts; index algebra checked).
// ---------------------------------------------------------------------------

// Merged prepass (R8-verified bodies): grid 3072 x 256.
__global__ void __launch_bounds__(256) prep_kernel(const float* __restrict__ x,
                                                   const uint32_t* __restrict__ qweight,
                                                   const uint32_t* __restrict__ qzeros,
                                                   const float* __restrict__ scales,
                                                   char* __restrict__ xImg,
                                                   char* __restrict__ wImg) {
  const int tid = threadIdx.x;
  if (blockIdx.x < 1024) {
    const int bid = blockIdx.x;
    const int mt = bid >> 6, ktp = bid & 63;
    const int row = tid & 127, sh = tid >> 7;
    const int s = ktp * 2 + sh;
    const float* src = x + (size_t)(mt * 128 + row) * K_DIM + s * 32;
    char* dst = xImg + (size_t)(mt * 128 + s) * 8192 + row * 16;
#pragma unroll
    for (int slot = 0; slot < 4; ++slot) {
      float4 f0 = *(const float4*)(src + slot * 8);
      float4 f1 = *(const float4*)(src + slot * 8 + 4);
      uint4 pk;
      pk.x = bf16pk(f0.x, f0.y);
      pk.y = bf16pk(f0.z, f0.w);
      pk.z = bf16pk(f1.x, f1.y);
      pk.w = bf16pk(f1.z, f1.w);
      *(uint4*)(dst + slot * 2048) = pk;
    }
  } else {
    const int bid = blockIdx.x - 1024;
    const int nt = bid >> 6, ktp = bid & 63;
    const int n = tid & 127, sh = tid >> 7;
    const int s = ktp * 2 + sh;
    const int g = ktp >> 1;                    // group = 128 k = 4 steps
    const int gn = nt * 128 + n;
    uint32_t zq = qzeros[g * (N_DIM / 8) + (gn >> 3)];
    const int z = (int)((zq >> ((gn & 7) * 4)) & 15u) + 1;
    const float s_ = scales[g * N_DIM + gn];
    char* dst = wImg + (size_t)(nt * 128 + s) * 8192 + n * 16;
#pragma unroll
    for (int slot = 0; slot < 4; ++slot) {
      uint32_t q = qweight[(size_t)(s * 4 + slot) * N_DIM + gn];
      float f[8];
#pragma unroll
      for (int v = 0; v < 8; ++v) {
        int w = (int)((q >> (4 * v)) & 15u);
        f[v] = (float)(w - z) * s_;            // exact int sub, cvt, mul
      }
      uint4 pk;
      pk.x = bf16pk(f[0], f[1]);
      pk.y = bf16pk(f[2], f[3]);
      pk.z = bf16pk(f[4], f[5]);
      pk.w = bf16pk(f[6], f[7]);
      *(uint4*)(dst + slot * 2048) = pk;
    }
  }
}

// ---------------------------------------------------------------------------
// GEMM: m201-style 8-phase 256^2 template, grid K-split 2.
// BM=BN=256, BK=64 (K-tile), 8 waves (2M x 4N), per-wave 128x64, 512 thr.
// grid 256 = 8 mb x 16 nb x 2 ks = 1 block/CU. LDS 128KB = 2 buf x 64KB;
// buffer = [Ak0 16K][Ak1 16K][Bk0 16K][Bk1 16K] (half-tile = 16KB = 2 glds).
//
// 8 phases / 2 K-tiles (T=2it in buf0, T+1 in buf1). Phase p:
//   {ds-reads (odd: 8 A + 2 B; even: 2 B) ; stage 1 half ; s_barrier ;
//    lgkmcnt(0)+schedbar ; setprio(1) ; 16 MFMA ; setprio(0) ;
//    [even phases: vmcnt(10)+schedbar] ; s_barrier}
// Stage slots (region freed >=1 barrier before issue -- checked per slot):
//   ph1:(T+1).Bk1->buf1  ph2:(T+2).Ak0->buf0  ph3:(T+2).Bk0->buf0
//   ph4:(T+2).Ak1->buf0  ph5:(T+2).Bk1->buf0  ph6:(T+3).Ak0->buf1
//   ph7:(T+3).Bk0->buf1  ph8:(T+3).Ak1->buf1
// vmcnt ledger (2 glds/half): steady outstanding at even-phase end = 7
// halves = 14 -> vmcnt(10) retires exactly the 2 halves the next odd phase
// reads. Every vmcnt precedes its barrier (cross-wave visibility, R7 rule).
// Prologue: t0 all + t1 {Ak0,Bk0,Ak1} (14 glds), vmcnt(6), barrier.
// Tail (it=15): stages only ph1 (31.Bk1); waits 8 @ph2, 4 @ph4, 0 @ph6.
// Epilogue: ks0 -> out+bias, ks1 -> part1; reduce kernel sums.
// ---------------------------------------------------------------------------
__global__ void __launch_bounds__(512, 1) gemm_kernel(const char* __restrict__ xImg,
                                                      const char* __restrict__ wImg,
                                                      const float* __restrict__ bias,
                                                      float* __restrict__ out,
                                                      float* __restrict__ part1) {
  __shared__ uint4 ldsv[8192];                 // 131072 B = 2 buf x 64KB
  char* lds = (char*)ldsv;
  const int tid = threadIdx.x;
  const int lane = tid & 63, wid = tid >> 6;
  const int wr = wid >> 2, wc = wid & 3;       // 2M x 4N
  const int lr = lane & 15, lk = lane >> 4;

  // 256 blocks: xcd-chunked bijective (256 % 8 == 0)
  const int bid = blockIdx.x;
  const int local = bid >> 3;                  // 0..31
  const int nb = (bid & 7) * 2 + (local & 1);  // 0..15
  const int mb = (local >> 1) & 7;             // 0..7
  const int ks = local >> 4;                   // 0..1

  f32x4 acc[8][4];
#pragma unroll
  for (int i = 0; i < 8; ++i)
#pragma unroll
    for (int j = 0; j < 4; ++j) acc[i][j] = f32x4{0.f, 0.f, 0.f, 0.f};

  const char* aT0 = xImg + ((size_t)(2 * mb) * 128 + ks * 64) * 8192;
  const char* aT1 = xImg + ((size_t)(2 * mb + 1) * 128 + ks * 64) * 8192;
  const char* bT0 = wImg + ((size_t)(2 * nb) * 128 + ks * 64) * 8192;
  const char* bT1 = wImg + ((size_t)(2 * nb + 1) * 128 + ks * 64) * 8192;

#define AH0(KT, KK) (aT0 + (size_t)(2 * (KT) + (KK)) * 8192)
#define AH1(KT, KK) (aT1 + (size_t)(2 * (KT) + (KK)) * 8192)
#define BH0(KT, KK) (bT0 + (size_t)(2 * (KT) + (KK)) * 8192)
#define BH1(KT, KK) (bT1 + (size_t)(2 * (KT) + (KK)) * 8192)

  // read offsets within a 16KB half
  int aoff[8], boff[4];
#pragma unroll
  for (int i = 0; i < 8; ++i) aoff[i] = wr * 8192 + lk * 2048 + (i * 16 + lr) * 16;
#pragma unroll
  for (int j = 0; j < 4; ++j)
    boff[j] = (wc >> 1) * 8192 + lk * 2048 + ((wc & 1) * 64 + j * 16 + lr) * 16;

#define STAGEHALF(S0, S1, D)                         \
  do {                                               \
    glds16((S0) + tid * 16, (D) + tid * 16);         \
    glds16((S1) + tid * 16, (D) + 8192 + tid * 16);  \
  } while (0)

  // PH: one phase. BASE=buf byte base, AK/BK=half offsets, JA/JB=cols,
  // RD=read A set, STG=stage statement, VM=vmcnt at end (-1 = none).
#define PH(BASE, AK, BK, JA, JB, RD, STG, VM)                                 \
  do {                                                                        \
    if (RD) {                                                                 \
      _Pragma("unroll") for (int i = 0; i < 8; ++i)                           \
          a[i] = *(const short8*)(lds + (BASE) + (AK) + aoff[i]);             \
    }                                                                         \
    bb0 = *(const short8*)(lds + (BASE) + (BK) + boff[JA]);                   \
    bb1 = *(const short8*)(lds + (BASE) + (BK) + boff[JB]);                   \
    STG;                                                                      \
    __builtin_amdgcn_s_barrier();                                             \
    asm volatile("s_waitcnt lgkmcnt(0)" ::: "memory");                        \
    __builtin_amdgcn_sched_barrier(0);                                        \
    __builtin_amdgcn_s_setprio(1);                                            \
    _Pragma("unroll") for (int i = 0; i < 8; ++i) {                           \
      acc[i][JA] = MFMA(a[i], bb0, acc[i][JA], 0, 0, 0);                      \
      acc[i][JB] = MFMA(a[i], bb1, acc[i][JB], 0, 0, 0);                      \
    }                                                                         \
    __builtin_amdgcn_s_setprio(0);                                            \
    if ((VM) == 10) asm volatile("s_waitcnt vmcnt(10)" ::: "memory");         \
    else if ((VM) == 8) asm volatile("s_waitcnt vmcnt(8)" ::: "memory");      \
    else if ((VM) == 4) asm volatile("s_waitcnt vmcnt(4)" ::: "memory");      \
    else if ((VM) == 0) asm volatile("s_waitcnt vmcnt(0)" ::: "memory");      \
    __builtin_amdgcn_sched_barrier(0);                                        \
    __builtin_amdgcn_s_barrier();                                             \
  } while (0)

  short8 a[8], bb0, bb1;

  // prologue: t0 {Ak0,Bk0,Ak1,Bk1} + t1 {Ak0,Bk0,Ak1} = 14 glds
  STAGEHALF(AH0(0, 0), AH1(0, 0), lds + 0);
  STAGEHALF(BH0(0, 0), BH1(0, 0), lds + 32768);
  STAGEHALF(AH0(0, 1), AH1(0, 1), lds + 16384);
  STAGEHALF(BH0(0, 1), BH1(0, 1), lds + 49152);
  STAGEHALF(AH0(1, 0), AH1(1, 0), lds + 65536);
  STAGEHALF(BH0(1, 0), BH1(1, 0), lds + 65536 + 32768);
  STAGEHALF(AH0(1, 1), AH1(1, 1), lds + 65536 + 16384);
  asm volatile("s_waitcnt vmcnt(6)" ::: "memory");   // t0 landed
  __builtin_amdgcn_sched_barrier(0);
  __builtin_amdgcn_s_barrier();

  for (int it = 0; it < 15; ++it) {
    const int T = 2 * it;
    PH(0, 0, 32768, 0, 1, true,
       STAGEHALF(BH0(T + 1, 1), BH1(T + 1, 1), lds + 65536 + 49152), -1);
    PH(0, 0, 32768, 2, 3, false,
       STAGEHALF(AH0(T + 2, 0), AH1(T + 2, 0), lds + 0), 10);
    PH(0, 16384, 49152, 0, 1, true,
       STAGEHALF(BH0(T + 2, 0), BH1(T + 2, 0), lds + 32768), -1);
    PH(0, 16384, 49152, 2, 3, false,
       STAGEHALF(AH0(T + 2, 1), AH1(T + 2, 1), lds + 16384), 10);
    PH(65536, 0, 32768, 0, 1, true,
       STAGEHALF(BH0(T + 2, 1), BH1(T + 2, 1), lds + 49152), -1);
    PH(65536, 0, 32768, 2, 3, false,
       STAGEHALF(AH0(T + 3, 0), AH1(T + 3, 0), lds + 65536), 10);
    PH(65536, 16384, 49152, 0, 1, true,
       STAGEHALF(BH0(T + 3, 0), BH1(T + 3, 0), lds + 65536 + 32768), -1);
    PH(65536, 16384, 49152, 2, 3, false,
       STAGEHALF(AH0(T + 3, 1), AH1(T + 3, 1), lds + 65536 + 16384), 10);
  }
  // tail it=15 (T=30): only ph1 stages (31.Bk1); waits 8/4/0
  PH(0, 0, 32768, 0, 1, true,
     STAGEHALF(BH0(31, 1), BH1(31, 1), lds + 65536 + 49152), -1);
  PH(0, 0, 32768, 2, 3, false, (void)0, 8);
  PH(0, 16384, 49152, 0, 1, true, (void)0, -1);
  PH(0, 16384, 49152, 2, 3, false, (void)0, 4);
  PH(65536, 0, 32768, 0, 1, true, (void)0, -1);
  PH(65536, 0, 32768, 2, 3, false, (void)0, 0);
  PH(65536, 16384, 49152, 0, 1, true, (void)0, -1);
  PH(65536, 16384, 49152, 2, 3, false, (void)0, -1);
#undef PH
#undef STAGEHALF
#undef AH0
#undef AH1
#undef BH0
#undef BH1

  // epilogue: C/D map col=lane&15, row=(lane>>4)*4+reg (verified R0-R13)
  float* dst = ks ? part1 : out;
  const int colB = nb * 256 + wc * 64 + lr;
  const int rowB = mb * 256 + wr * 128 + lk * 4;
#pragma unroll
  for (int j = 0; j < 4; ++j) {
    int col = colB + j * 16;
    float bj = (ks == 0) ? bias[col] : 0.f;
#pragma unroll
    for (int i = 0; i < 8; ++i) {
      int row = rowB + i * 16;
#pragma unroll
      for (int r = 0; r < 4; ++r)
        dst[(size_t)(row + r) * N_DIM + col] = acc[i][j][r] + bj;
    }
  }
}

// out += part1 (R3-verified)
__global__ void __launch_bounds__(256) reduce_kernel(float* __restrict__ out,
                                                     const float* __restrict__ part1) {
  int i = blockIdx.x * 256 + threadIdx.x;
  float4 o = ((const float4*)out)[i];
  float4 p = ((const float4*)part1)[i];
  o.x += p.x; o.y += p.y; o.z += p.z; o.w += p.w;
  ((float4*)out)[i] = o;
}

// ---------------------------------------------------------------------------
// Fallback (workspace too small)
// ---------------------------------------------------------------------------
__global__ void fallback_kernel(const float* __restrict__ x, const uint32_t* __restrict__ qweight,
                                const uint32_t* __restrict__ qzeros, const float* __restrict__ scales,
                                const float* __restrict__ bias, float* __restrict__ out) {
  __shared__ float xs[16][17];
  __shared__ float ws[16][17];
  int tx = threadIdx.x, ty = threadIdx.y;
  int col = blockIdx.x * 16 + tx;
  int row = blockIdx.y * 16 + ty;
  float acc = 0.f;
  for (int k0 = 0; k0 < K_DIM; k0 += 16) {
    xs[ty][tx] = x[(size_t)row * K_DIM + k0 + tx];
    int k = k0 + ty;
    int g = k >> 7;
    uint32_t q = qweight[(size_t)(k >> 3) * N_DIM + col];
    int w = (int)((q >> ((k & 7) * 4)) & 15u);
    uint32_t zq = qzeros[g * (N_DIM / 8) + (col >> 3)];
    int z = (int)((zq >> ((col & 7) * 4)) & 15u) + 1;
    ws[ty][tx] = (float)(w - z) * scales[g * N_DIM + col];
    __syncthreads();
#pragma unroll
    for (int kk = 0; kk < 16; ++kk) acc += xs[ty][kk] * ws[kk][tx];
    __syncthreads();
  }
  out[(size_t)row * N_DIM + col] = acc + bias[col];
}

extern "C" void kernel_launch(void* const* d_in, const int* in_sizes, int n_in,
                              void* d_out, int out_size, void* d_ws, size_t ws_size,
                              hipStream_t stream) {
  const float* x = (const float*)d_in[0];
  const uint32_t* qweight = (const uint32_t*)d_in[1];
  const uint32_t* qzeros = (const uint32_t*)d_in[2];
  const float* scales = (const float*)d_in[3];
  // d_in[4] = g_idx (== arange(K)//128, folded into index math)
  const float* bias = (const float*)d_in[5];
  float* out = (float*)d_out;

  const size_t X_IMG = (size_t)16 * 128 * 8192;   // 16.78 MB
  const size_t W_IMG = (size_t)32 * 128 * 8192;   // 33.55 MB
  const size_t PART = (size_t)M_DIM * N_DIM * 4;  // 33.55 MB

  if (ws_size >= X_IMG + W_IMG + PART) {
    char* xImg = (char*)d_ws;
    char* wImg = (char*)d_ws + X_IMG;
    float* part1 = (float*)((char*)d_ws + X_IMG + W_IMG);
    prep_kernel<<<3072, 256, 0, stream>>>(x, qweight, qzeros, scales, xImg, wImg);
    gemm_kernel<<<256, 512, 0, stream>>>(xImg, wImg, bias, out, part1);
    reduce_kernel<<<8192, 256, 0, stream>>>(out, part1);
  } else {
    fallback_kernel<<<dim3(N_DIM / 16, M_DIM / 16), dim3(16, 16), 0, stream>>>(
        x, qweight, qzeros, scales, bias, out);
  }
}

// Round 15
// 83.768 us; speedup vs baseline: 1.3968x; 1.1603x over previous
//
#include <hip/hip_runtime.h>
#include <hip/hip_bf16.h>
#include <stdint.h>

#define M_DIM 2048
#define K_DIM 4096
#define N_DIM 4096

typedef __attribute__((ext_vector_type(8))) short short8;
typedef __attribute__((ext_vector_type(4))) float f32x4;

#define MFMA __builtin_amdgcn_mfma_f32_16x16x32_bf16

// RNE float -> bf16, packed pair
__device__ __forceinline__ uint32_t bf16pk(float a, float b) {
  uint32_t ua = __float_as_uint(a);
  ua = (ua + 0x7FFFu + ((ua >> 16) & 1u)) >> 16;
  uint32_t ub = __float_as_uint(b);
  ub = (ub + 0x7FFFu + ((ub >> 16) & 1u)) >> 16;
  return ua | (ub << 16);
}

__device__ __forceinline__ void glds16(const char* g, char* l) {
  __builtin_amdgcn_global_load_lds((__attribute__((address_space(1))) void*)g,
                                   (__attribute__((address_space(3))) void*)l, 16, 0, 0);
}

// ---------------------------------------------------------------------------
// Image layout: BK=32 steps, 8KB tiles, [k8-slot 0..3][row 0..127][16B].
//  xImg[mt 0..15][step 0..127]  (16.78 MB)
//  wImg[nt 0..31][step 0..127]  (33.55 MB)
// Verified R6-R14 (0 bank conflicts; index algebra checked).
// ---------------------------------------------------------------------------

// Merged prepass (R8-verified bodies): grid 3072 x 256.
__global__ void __launch_bounds__(256) prep_kernel(const float* __restrict__ x,
                                                   const uint32_t* __restrict__ qweight,
                                                   const uint32_t* __restrict__ qzeros,
                                                   const float* __restrict__ scales,
                                                   char* __restrict__ xImg,
                                                   char* __restrict__ wImg) {
  const int tid = threadIdx.x;
  if (blockIdx.x < 1024) {
    const int bid = blockIdx.x;
    const int mt = bid >> 6, ktp = bid & 63;
    const int row = tid & 127, sh = tid >> 7;
    const int s = ktp * 2 + sh;
    const float* src = x + (size_t)(mt * 128 + row) * K_DIM + s * 32;
    char* dst = xImg + (size_t)(mt * 128 + s) * 8192 + row * 16;
#pragma unroll
    for (int slot = 0; slot < 4; ++slot) {
      float4 f0 = *(const float4*)(src + slot * 8);
      float4 f1 = *(const float4*)(src + slot * 8 + 4);
      uint4 pk;
      pk.x = bf16pk(f0.x, f0.y);
      pk.y = bf16pk(f0.z, f0.w);
      pk.z = bf16pk(f1.x, f1.y);
      pk.w = bf16pk(f1.z, f1.w);
      *(uint4*)(dst + slot * 2048) = pk;
    }
  } else {
    const int bid = blockIdx.x - 1024;
    const int nt = bid >> 6, ktp = bid & 63;
    const int n = tid & 127, sh = tid >> 7;
    const int s = ktp * 2 + sh;
    const int g = ktp >> 1;                    // group = 128 k = 4 steps
    const int gn = nt * 128 + n;
    uint32_t zq = qzeros[g * (N_DIM / 8) + (gn >> 3)];
    const int z = (int)((zq >> ((gn & 7) * 4)) & 15u) + 1;
    const float s_ = scales[g * N_DIM + gn];
    char* dst = wImg + (size_t)(nt * 128 + s) * 8192 + n * 16;
#pragma unroll
    for (int slot = 0; slot < 4; ++slot) {
      uint32_t q = qweight[(size_t)(s * 4 + slot) * N_DIM + gn];
      float f[8];
#pragma unroll
      for (int v = 0; v < 8; ++v) {
        int w = (int)((q >> (4 * v)) & 15u);
        f[v] = (float)(w - z) * s_;            // exact int sub, cvt, mul
      }
      uint4 pk;
      pk.x = bf16pk(f[0], f[1]);
      pk.y = bf16pk(f[2], f[3]);
      pk.z = bf16pk(f[4], f[5]);
      pk.w = bf16pk(f[6], f[7]);
      *(uint4*)(dst + slot * 2048) = pk;
    }
  }
}

// ---------------------------------------------------------------------------
// GEMM: R11 structure + vmcnt-ledger repair (the B-direct build, fixed).
// Diagnosis: R8 is LDS-port-saturated (demand 127 B/cyc > 112 measured
// ceiling). B-direct (R11) drops demand to 76 B/cyc but its end-of-step
// vmcnt(0) drained the just-issued B(t+1) prefetch -> L2 latency exposed
// every step. Fix: issue A-stage glds FIRST, B(t+1) loads second (order
// pinned by sched_barrier), and wait vmcnt(4) -- in-order retire drains
// exactly the A-stage (needed pre-barrier) while B(t+1) stays in flight a
// full step before use.
//
// Queue induction (4 glds A-stage + 4 loads B per step):
//   end of step t-1: outstanding = [B(t) x4]
//   step t top: +[Astage(t+1) x4, B(t+1) x4] -> 12
//   first MFMA uses B(t): compiler emits vmcnt(8) (satisfied, ~1200cy old)
//   step t end: vmcnt(4) retires [B(t) left? no - retired by use-wait]
//     -> retires Astage(t+1) (oldest remaining), leaves B(t+1) x4. QED.
// BM=BN=128, 4 waves (2ks x 2wc), per-wave 128x64, in-block K-split,
// LDS-exchange epilogue, grid 512 -> 2 blocks/CU. A ring-2 x 16KB.
// ---------------------------------------------------------------------------
__global__ void __launch_bounds__(256, 2) gemm_kernel(const char* __restrict__ xImg,
                                                      const char* __restrict__ wImg,
                                                      const float* __restrict__ bias,
                                                      float* __restrict__ out) {
  __shared__ uint4 ldsv[4096];                 // 65536 B (ring [0,32K); epi all)
  char* lds = (char*)ldsv;
  const int tid = threadIdx.x;
  const int lane = tid & 63, wid = tid >> 6;
  const int ks = wid >> 1, wc = wid & 1;       // ks-half, N-half
  const int lr = lane & 15, lk = lane >> 4;

  // XCD-chunked bijective swizzle (512 % 8 == 0)
  const int bid = blockIdx.x;
  const int wg = (bid & 7) * 64 + (bid >> 3);
  const int mb = wg & 15, nb = wg >> 4;        // mb 0..15, nb 0..31

  f32x4 acc[8][4];
#pragma unroll
  for (int i = 0; i < 8; ++i)
#pragma unroll
    for (int j = 0; j < 4; ++j) acc[i][j] = f32x4{0.f, 0.f, 0.f, 0.f};

  const char* aT0 = xImg + (size_t)mb * 128 * 8192;
  const char* aT1 = aT0 + (size_t)64 * 8192;   // ks=1 K-half
  // per-wave B source (global, L2-resident): step t at +t*8192, col j at +j*256
  const char* bW = wImg + (size_t)(nb * 128 + ks * 64) * 8192 + lk * 2048 + (wc * 64 + lr) * 16;

  int aoff[8];
#pragma unroll
  for (int i = 0; i < 8; ++i) aoff[i] = ks * 8192 + lk * 2048 + (i * 16 + lr) * 16;

#define STAGE(T, SB)                                                     \
  do {                                                                   \
    char* d = lds + (SB);                                                \
    const char* sa0 = aT0 + (size_t)(T) * 8192;                          \
    const char* sa1 = aT1 + (size_t)(T) * 8192;                          \
    glds16(sa0 + tid * 16, d + tid * 16);                                \
    glds16(sa0 + 4096 + tid * 16, d + 4096 + tid * 16);                  \
    glds16(sa1 + tid * 16, d + 8192 + tid * 16);                         \
    glds16(sa1 + 4096 + tid * 16, d + 12288 + tid * 16);                 \
  } while (0)

  // prologue: A-stage(0) FIRST, then B(0) prefetch; vmcnt(0) once; barrier
  STAGE(0, 0);
  __builtin_amdgcn_sched_barrier(0);
  short8 bc0 = *(const short8*)(bW);
  short8 bc1 = *(const short8*)(bW + 256);
  short8 bc2 = *(const short8*)(bW + 512);
  short8 bc3 = *(const short8*)(bW + 768);
  asm volatile("s_waitcnt vmcnt(0)" ::: "memory");
  __builtin_amdgcn_sched_barrier(0);
  __builtin_amdgcn_s_barrier();

#pragma unroll 2
  for (int t = 0; t < 64; ++t) {
    const char* buf = lds + (t & 1) * 16384;

    // 1. A-stage(t+1) FIRST (glds), order-pinned, then B(t+1) prefetch.
    short8 bn0, bn1, bn2, bn3;
    if (t < 63) {
      STAGE(t + 1, ((t + 1) & 1) * 16384);
      __builtin_amdgcn_sched_barrier(0);       // pin: A-stage older than B
      const char* bS = bW + (size_t)(t + 1) * 8192;
      bn0 = *(const short8*)(bS);
      bn1 = *(const short8*)(bS + 256);
      bn2 = *(const short8*)(bS + 512);
      bn3 = *(const short8*)(bS + 768);
    }
    __builtin_amdgcn_sched_barrier(0);

    // 2. A ds_reads
    short8 a0 = *(const short8*)(buf + aoff[0]);
    short8 a1 = *(const short8*)(buf + aoff[1]);
    short8 a2 = *(const short8*)(buf + aoff[2]);
    short8 a3 = *(const short8*)(buf + aoff[3]);
    short8 a4 = *(const short8*)(buf + aoff[4]);
    short8 a5 = *(const short8*)(buf + aoff[5]);
    short8 a6 = *(const short8*)(buf + aoff[6]);
    short8 a7 = *(const short8*)(buf + aoff[7]);

    asm volatile("s_waitcnt lgkmcnt(4)" ::: "memory");
    __builtin_amdgcn_sched_barrier(0);
    __builtin_amdgcn_s_setprio(1);
    acc[0][0] = MFMA(a0, bc0, acc[0][0], 0, 0, 0);
    acc[1][0] = MFMA(a1, bc0, acc[1][0], 0, 0, 0);
    acc[2][0] = MFMA(a2, bc0, acc[2][0], 0, 0, 0);
    acc[3][0] = MFMA(a3, bc0, acc[3][0], 0, 0, 0);
    acc[0][1] = MFMA(a0, bc1, acc[0][1], 0, 0, 0);
    acc[1][1] = MFMA(a1, bc1, acc[1][1], 0, 0, 0);
    acc[2][1] = MFMA(a2, bc1, acc[2][1], 0, 0, 0);
    acc[3][1] = MFMA(a3, bc1, acc[3][1], 0, 0, 0);
    acc[0][2] = MFMA(a0, bc2, acc[0][2], 0, 0, 0);
    acc[1][2] = MFMA(a1, bc2, acc[1][2], 0, 0, 0);
    acc[2][2] = MFMA(a2, bc2, acc[2][2], 0, 0, 0);
    acc[3][2] = MFMA(a3, bc2, acc[3][2], 0, 0, 0);
    acc[0][3] = MFMA(a0, bc3, acc[0][3], 0, 0, 0);
    acc[1][3] = MFMA(a1, bc3, acc[1][3], 0, 0, 0);
    acc[2][3] = MFMA(a2, bc3, acc[2][3], 0, 0, 0);
    acc[3][3] = MFMA(a3, bc3, acc[3][3], 0, 0, 0);
    asm volatile("s_waitcnt lgkmcnt(0)" ::: "memory");
    __builtin_amdgcn_sched_barrier(0);
    acc[4][0] = MFMA(a4, bc0, acc[4][0], 0, 0, 0);
    acc[5][0] = MFMA(a5, bc0, acc[5][0], 0, 0, 0);
    acc[6][0] = MFMA(a6, bc0, acc[6][0], 0, 0, 0);
    acc[7][0] = MFMA(a7, bc0, acc[7][0], 0, 0, 0);
    acc[4][1] = MFMA(a4, bc1, acc[4][1], 0, 0, 0);
    acc[5][1] = MFMA(a5, bc1, acc[5][1], 0, 0, 0);
    acc[6][1] = MFMA(a6, bc1, acc[6][1], 0, 0, 0);
    acc[7][1] = MFMA(a7, bc1, acc[7][1], 0, 0, 0);
    acc[4][2] = MFMA(a4, bc2, acc[4][2], 0, 0, 0);
    acc[5][2] = MFMA(a5, bc2, acc[5][2], 0, 0, 0);
    acc[6][2] = MFMA(a6, bc2, acc[6][2], 0, 0, 0);
    acc[7][2] = MFMA(a7, bc2, acc[7][2], 0, 0, 0);
    acc[4][3] = MFMA(a4, bc3, acc[4][3], 0, 0, 0);
    acc[5][3] = MFMA(a5, bc3, acc[5][3], 0, 0, 0);
    acc[6][3] = MFMA(a6, bc3, acc[6][3], 0, 0, 0);
    acc[7][3] = MFMA(a7, bc3, acc[7][3], 0, 0, 0);
    __builtin_amdgcn_s_setprio(0);

    if (t < 63) {
      // vmcnt(4): retires own A-stage(t+1) (oldest 4); B(t+1) stays in flight.
      asm volatile("s_waitcnt vmcnt(4)" ::: "memory");
      __builtin_amdgcn_sched_barrier(0);
      __builtin_amdgcn_s_barrier();            // globalize A-stage
      bc0 = bn0; bc1 = bn1; bc2 = bn2; bc3 = bn3;  // renamed by unroll
    }
  }
#undef STAGE

  // ---- epilogue: in-block cross-ks reduction via LDS exchange (R8) ----
  __syncthreads();   // all K-loop LDS reads done; ring space free
  if (ks == 1) {
#pragma unroll
    for (int i = 0; i < 4; ++i)
#pragma unroll
      for (int j = 0; j < 4; ++j)
        *(f32x4*)(lds + (wc * 16 + i * 4 + j) * 1024 + lane * 16) = acc[i][j];
  } else {
#pragma unroll
    for (int i = 4; i < 8; ++i)
#pragma unroll
      for (int j = 0; j < 4; ++j)
        *(f32x4*)(lds + 32768 + (wc * 16 + (i - 4) * 4 + j) * 1024 + lane * 16) = acc[i][j];
  }
  __syncthreads();

  // C/D map col=lane&15, row=(lane>>4)*4+reg (verified R0-R14)
  const int colB = nb * 128 + wc * 64 + lr;
  if (ks == 0) {
#pragma unroll
    for (int j = 0; j < 4; ++j) {
      int col = colB + j * 16;
      float bj = bias[col];
#pragma unroll
      for (int i = 0; i < 4; ++i) {
        f32x4 p = *(const f32x4*)(lds + (wc * 16 + i * 4 + j) * 1024 + lane * 16);
        int row = mb * 128 + i * 16 + lk * 4;
#pragma unroll
        for (int r = 0; r < 4; ++r)
          out[(size_t)(row + r) * N_DIM + col] = acc[i][j][r] + p[r] + bj;
      }
    }
  } else {
#pragma unroll
    for (int j = 0; j < 4; ++j) {
      int col = colB + j * 16;
      float bj = bias[col];
#pragma unroll
      for (int i = 4; i < 8; ++i) {
        f32x4 p = *(const f32x4*)(lds + 32768 + (wc * 16 + (i - 4) * 4 + j) * 1024 + lane * 16);
        int row = mb * 128 + i * 16 + lk * 4;
#pragma unroll
        for (int r = 0; r < 4; ++r)
          out[(size_t)(row + r) * N_DIM + col] = acc[i][j][r] + p[r] + bj;
      }
    }
  }
}

// ---------------------------------------------------------------------------
// Fallback (workspace too small)
// ---------------------------------------------------------------------------
__global__ void fallback_kernel(const float* __restrict__ x, const uint32_t* __restrict__ qweight,
                                const uint32_t* __restrict__ qzeros, const float* __restrict__ scales,
                                const float* __restrict__ bias, float* __restrict__ out) {
  __shared__ float xs[16][17];
  __shared__ float ws[16][17];
  int tx = threadIdx.x, ty = threadIdx.y;
  int col = blockIdx.x * 16 + tx;
  int row = blockIdx.y * 16 + ty;
  float acc = 0.f;
  for (int k0 = 0; k0 < K_DIM; k0 += 16) {
    xs[ty][tx] = x[(size_t)row * K_DIM + k0 + tx];
    int k = k0 + ty;
    int g = k >> 7;
    uint32_t q = qweight[(size_t)(k >> 3) * N_DIM + col];
    int w = (int)((q >> ((k & 7) * 4)) & 15u);
    uint32_t zq = qzeros[g * (N_DIM / 8) + (col >> 3)];
    int z = (int)((zq >> ((col & 7) * 4)) & 15u) + 1;
    ws[ty][tx] = (float)(w - z) * scales[g * N_DIM + col];
    __syncthreads();
#pragma unroll
    for (int kk = 0; kk < 16; ++kk) acc += xs[ty][kk] * ws[kk][tx];
    __syncthreads();
  }
  out[(size_t)row * N_DIM + col] = acc + bias[col];
}

extern "C" void kernel_launch(void* const* d_in, const int* in_sizes, int n_in,
                              void* d_out, int out_size, void* d_ws, size_t ws_size,
                              hipStream_t stream) {
  const float* x = (const float*)d_in[0];
  const uint32_t* qweight = (const uint32_t*)d_in[1];
  const uint32_t* qzeros = (const uint32_t*)d_in[2];
  const float* scales = (const float*)d_in[3];
  // d_in[4] = g_idx (== arange(K)//128, folded into index math)
  const float* bias = (const float*)d_in[5];
  float* out = (float*)d_out;

  const size_t X_IMG = (size_t)16 * 128 * 8192;   // 16.78 MB
  const size_t W_IMG = (size_t)32 * 128 * 8192;   // 33.55 MB

  if (ws_size >= X_IMG + W_IMG) {
    char* xImg = (char*)d_ws;
    char* wImg = (char*)d_ws + X_IMG;
    prep_kernel<<<3072, 256, 0, stream>>>(x, qweight, qzeros, scales, xImg, wImg);
    gemm_kernel<<<512, 256, 0, stream>>>(xImg, wImg, bias, out);
  } else {
    fallback_kernel<<<dim3(N_DIM / 16, M_DIM / 16), dim3(16, 16), 0, stream>>>(
        x, qweight, qzeros, scales, bias, out);
  }
}